// Round 2
// baseline (125.921 us; speedup 1.0000x reference)
//
#include <hip/hip_runtime.h>

// Shape fixed by the reference: data/mask [B,T,D] float32.
#define BB 8
#define TT 4096
#define DD 1024
#define D4 256           // DD/4 float4 columns
#define LL 16            // chunk length along T
#define CC 256           // TT/LL chunks
#define GG 16            // chunk groups
#define CPG 16           // chunks per group (CC = GG*CPG)

// ---------------------------------------------------------------------------
// A: per (b, chunk, d4) last-valid-in-chunk via backward early-exit scan.
// Expected ~2.4 iterations/wave at 10% missing. Coalesced (lanes over d4).
// ---------------------------------------------------------------------------
__global__ __launch_bounds__(256) void ffA(
    const float4* __restrict__ data, const float4* __restrict__ mask,
    float4* __restrict__ carryV, unsigned char* __restrict__ carryF) {
  int tid = blockIdx.x * 256 + threadIdx.x;  // B*CC*D4 = 524288
  int d4 = tid & (D4 - 1);
  int bc = tid >> 8;  // b*CC + c

  float4 val = make_float4(0.f, 0.f, 0.f, 0.f);
  int found = 0;
  long base = ((long)bc * LL + (LL - 1)) * D4 + d4;
  for (int i = LL - 1; i >= 0 && found != 0xF; --i, base -= D4) {
    float4 m = mask[base];
    float4 v = data[base];
    if (!(found & 1) && m.x > 0.f) { val.x = v.x; found |= 1; }
    if (!(found & 2) && m.y > 0.f) { val.y = v.y; found |= 2; }
    if (!(found & 4) && m.z > 0.f) { val.z = v.z; found |= 4; }
    if (!(found & 8) && m.w > 0.f) { val.w = v.w; found |= 8; }
  }
  carryV[tid] = val;
  carryF[tid] = (unsigned char)found;
}

// ---------------------------------------------------------------------------
// B: within-group exclusive prefix, IN PLACE over carryV/F, plus group carry.
// One thread per (b, group, d4); coalesced; 128 blocks.
// ---------------------------------------------------------------------------
__global__ __launch_bounds__(256) void ffB(
    float4* __restrict__ carryV, unsigned char* __restrict__ carryF,
    float4* __restrict__ gV, unsigned char* __restrict__ gF) {
  int tid = blockIdx.x * 256 + threadIdx.x;  // B*GG*D4 = 32768
  int d4 = tid & (D4 - 1);
  int bg = tid >> 8;  // b*GG + g

  float4 run = make_float4(0.f, 0.f, 0.f, 0.f);
  int rf = 0;
  long k = (long)bg * CPG * D4 + d4;  // == (b*CC + g*CPG)*D4 + d4
  for (int c = 0; c < CPG; ++c, k += D4) {
    float4 v = carryV[k];
    int f = carryF[k];
    carryV[k] = run;                 // exclusive local prefix
    carryF[k] = (unsigned char)rf;
    if (f & 1) run.x = v.x;
    if (f & 2) run.y = v.y;
    if (f & 4) run.z = v.z;
    if (f & 8) run.w = v.w;
    rf |= f;
  }
  gV[tid] = run;
  gF[tid] = (unsigned char)rf;
}

// ---------------------------------------------------------------------------
// C: exclusive scan over the 16 group carries per (b, d4). "No valid yet"
// is representable as FILL_VALUE=0.0, so gcin needs no flags. Tiny.
// ---------------------------------------------------------------------------
__global__ __launch_bounds__(256) void ffC(
    const float4* __restrict__ gV, const unsigned char* __restrict__ gF,
    float4* __restrict__ gcin) {
  int tid = blockIdx.x * 256 + threadIdx.x;  // B*D4 = 2048
  int d4 = tid & (D4 - 1);
  int b = tid >> 8;

  float4 run = make_float4(0.f, 0.f, 0.f, 0.f);
  long k = (long)b * GG * D4 + d4;
  for (int g = 0; g < GG; ++g, k += D4) {
    gcin[k] = run;
    float4 v = gV[k];
    int f = gF[k];
    if (f & 1) run.x = v.x;
    if (f & 2) run.y = v.y;
    if (f & 4) run.z = v.z;
    if (f & 8) run.w = v.w;
  }
}

// ---------------------------------------------------------------------------
// D (dominant): carry-in = group-carry-in overridden by local prefix, then
// stream the fill. 2048 blocks = 8/CU, 32 waves/CU. Mask pass-through fused.
// ---------------------------------------------------------------------------
__global__ __launch_bounds__(256) void ffD(
    const float4* __restrict__ data, const float4* __restrict__ mask,
    const float4* __restrict__ cinLV, const unsigned char* __restrict__ cinLF,
    const float4* __restrict__ gcin, float4* __restrict__ outf,
    float4* __restrict__ outm) {
  int tid = blockIdx.x * 256 + threadIdx.x;  // B*CC*D4 = 524288
  int d4 = tid & (D4 - 1);
  int bc = tid >> 8;        // b*CC + c
  int b = bc >> 8;
  int c = bc & (CC - 1);
  int g = c >> 4;

  float4 last = gcin[((long)b * GG + g) * D4 + d4];
  float4 lv = cinLV[tid];
  int lf = cinLF[tid];
  if (lf & 1) last.x = lv.x;
  if (lf & 2) last.y = lv.y;
  if (lf & 4) last.z = lv.z;
  if (lf & 8) last.w = lv.w;

  long base = (long)bc * LL * D4 + d4;
#pragma unroll 4
  for (int i = 0; i < LL; ++i, base += D4) {
    float4 m = mask[base];
    float4 v = data[base];
    last.x = (m.x > 0.f) ? v.x : last.x;
    last.y = (m.y > 0.f) ? v.y : last.y;
    last.z = (m.z > 0.f) ? v.z : last.z;
    last.w = (m.w > 0.f) ? v.w : last.w;
    outf[base] = last;
    outm[base] = m;
  }
}

// ---------------------------------------------------------------------------
// Fallback if workspace is too small: one thread per (b, d4) full-column scan.
// ---------------------------------------------------------------------------
__global__ __launch_bounds__(256) void ff_naive(
    const float4* __restrict__ data, const float4* __restrict__ mask,
    float4* __restrict__ outf, float4* __restrict__ outm) {
  int tid = blockIdx.x * blockDim.x + threadIdx.x;
  if (tid >= BB * D4) return;
  int d4 = tid & (D4 - 1);
  int b = tid / D4;

  float4 last = make_float4(0.f, 0.f, 0.f, 0.f);
  long base = (long)b * TT * D4 + d4;
  for (int t = 0; t < TT; ++t, base += D4) {
    float4 m = mask[base];
    float4 v = data[base];
    last.x = (m.x > 0.f) ? v.x : last.x;
    last.y = (m.y > 0.f) ? v.y : last.y;
    last.z = (m.z > 0.f) ? v.z : last.z;
    last.w = (m.w > 0.f) ? v.w : last.w;
    outf[base] = last;
    outm[base] = m;
  }
}

extern "C" void kernel_launch(void* const* d_in, const int* in_sizes, int n_in,
                              void* d_out, int out_size, void* d_ws, size_t ws_size,
                              hipStream_t stream) {
  const float4* data = (const float4*)d_in[0];
  const float4* mask = (const float4*)d_in[1];
  const long N = (long)BB * TT * DD;
  float4* outf = (float4*)d_out;
  float4* outm = (float4*)((float*)d_out + N);

  // Workspace layout (float4 arrays first for alignment):
  const size_t nCarry = (size_t)BB * CC * D4;   // 524288
  const size_t nGrp = (size_t)BB * GG * D4;     // 32768
  const size_t bytes_carryV = nCarry * sizeof(float4);  // 8 MiB
  const size_t bytes_gV = nGrp * sizeof(float4);        // 512 KiB
  const size_t bytes_gcin = nGrp * sizeof(float4);      // 512 KiB
  const size_t bytes_carryF = nCarry;                   // 512 KiB
  const size_t bytes_gF = nGrp;                         // 32 KiB
  const size_t need =
      bytes_carryV + bytes_gV + bytes_gcin + bytes_carryF + bytes_gF;

  if (ws_size >= need) {
    char* p = (char*)d_ws;
    float4* carryV = (float4*)p;             p += bytes_carryV;
    float4* gV = (float4*)p;                 p += bytes_gV;
    float4* gcin = (float4*)p;               p += bytes_gcin;
    unsigned char* carryF = (unsigned char*)p; p += bytes_carryF;
    unsigned char* gF = (unsigned char*)p;

    ffA<<<(int)(nCarry / 256), 256, 0, stream>>>(data, mask, carryV, carryF);
    ffB<<<(int)(nGrp / 256), 256, 0, stream>>>(carryV, carryF, gV, gF);
    ffC<<<(BB * D4) / 256, 256, 0, stream>>>(gV, gF, gcin);
    ffD<<<(int)(nCarry / 256), 256, 0, stream>>>(data, mask, carryV, carryF,
                                                 gcin, outf, outm);
  } else {
    ff_naive<<<(BB * D4 + 255) / 256, 256, 0, stream>>>(data, mask, outf, outm);
  }
}